// Round 10
// baseline (688.384 us; speedup 1.0000x reference)
//
#include <hip/hip_runtime.h>
#include <hip/hip_bf16.h>

// GCN 4-layer, linear network => collapse to:
// out = A^4 x0 * c4 + A^3 1 * c3 + A^2 1 * c2 + A 1 * c1 + b4,
// A = D^-1/2 (Adj+I) D^-1/2. Propagate in scaled space u' = D^-1 (A+I) u,
// epilogue multiplies sqrt(deg). Dtypes (R1-R4 verified): read_length int32,
// edge_index int32, W/b fp32, out fp32.
//
// R10: gathers are 75% of runtime (~120us/pass, unchanged by halving vin to
// 2MB in R9 -> footprint theory dead). Revised model: random 4B gathers are
// L1-miss-machinery bound (~0.1 ld/cyc/CU = ~20 outstanding x 200cyc L2 hit;
// L1 hit rate on vin ~1.5%, pure overhead). Fix under test: nt loads
// (__builtin_nontemporal_load) to bypass L1 allocation on vin gathers + all
// edge streams, and 8-deep unroll to fill the deeper queue. Scatter/count
// streams also nt so they stop evicting open store lines / vin in L2.

#define BLK  256
#define SBLK 1024         // scatter/count/gather block
#define NB   512          // buckets
#define BSH  10           // bucket = dst >> 10  (1024 nodes / bucket)
#define PB   256          // partition blocks

#define NTL(p) __builtin_nontemporal_load(p)

// ---- manual bf16 pack/unpack (RNE), no API dependency
__device__ __forceinline__ unsigned f2bf(float f) {
    unsigned u = __float_as_uint(f);
    return (u + 0x7FFFu + ((u >> 16) & 1u)) >> 16;
}
__device__ __forceinline__ float bf2f(unsigned h) {
    return __uint_as_float(h << 16);
}
__device__ __forceinline__ unsigned packbf2(float x, float y) {
    return (f2bf(y) << 16) | f2bf(x);
}

// If rl were int64 (values in [0,20000)), every odd int32 word is 0.
__global__ void probe_i64(const int* __restrict__ rl32, int* __restrict__ flag) {
    int acc = 0;
    for (int k = threadIdx.x; k < 1024; k += blockDim.x)
        acc |= rl32[2 * k + 1];
    if (acc != 0) atomicOr(flag, 1);   // 1 => int32 layout
}

__global__ __launch_bounds__(SBLK)
void bucket_count(const int* __restrict__ dst, int* __restrict__ table, int E) {
    __shared__ int h[NB];
    int j = blockIdx.x, t = threadIdx.x;
    for (int b = t; b < NB; b += SBLK) h[b] = 0;
    __syncthreads();
    int chunk = (E + PB - 1) / PB;
    int beg = j * chunk, end = min(beg + chunk, E);
    for (int e = beg + t; e < end; e += SBLK)
        atomicAdd(&h[((unsigned)NTL(&dst[e])) >> BSH], 1);
    __syncthreads();
    for (int b = t; b < NB; b += SBLK) table[j * NB + b] = h[b];   // coalesced
}

__global__ void bucket_tot(const int* __restrict__ table, int* __restrict__ tot) {
    int b = blockIdx.x * blockDim.x + threadIdx.x;   // NB threads
    if (b >= NB) return;
    int s = 0;
    for (int j = 0; j < PB; ++j) s += table[j * NB + b];  // coalesced rows
    tot[b] = s;
}

__global__ void scan_base(const int* __restrict__ tot, int* __restrict__ base) {
    __shared__ int sm[BLK];
    int t = threadIdx.x;
    int loc[NB / BLK]; int s = 0;
#pragma unroll
    for (int k = 0; k < NB / BLK; ++k) { loc[k] = tot[t * (NB / BLK) + k]; s += loc[k]; }
    sm[t] = s; __syncthreads();
    int v = s;
    for (int off = 1; off < BLK; off <<= 1) {
        int add = (t >= off) ? sm[t - off] : 0;
        __syncthreads(); sm[t] += add; __syncthreads();
    }
    int run = sm[t] - v;   // exclusive across threads
#pragma unroll
    for (int k = 0; k < NB / BLK; ++k) { base[t * (NB / BLK) + k] = run; run += loc[k]; }
    if (t == BLK - 1) base[NB] = run;   // == E
}

// in-place: table[j][b] := bucket_base[b] + sum_{j'<j} table[j'][b]
__global__ void scan_table(int* __restrict__ table, const int* __restrict__ base) {
    int b = blockIdx.x * blockDim.x + threadIdx.x;
    if (b >= NB) return;
    int run = base[b];
    for (int j = 0; j < PB; ++j) {       // coalesced read+write per j
        int v = table[j * NB + b];
        table[j * NB + b] = run;
        run += v;
    }
}

__global__ __launch_bounds__(SBLK)
void scatter(const int* __restrict__ src, const int* __restrict__ dst,
             const int* __restrict__ table, unsigned* __restrict__ epart, int E) {
    __shared__ int cur[NB];
    int j = blockIdx.x, t = threadIdx.x;
    for (int b = t; b < NB; b += SBLK) cur[b] = table[j * NB + b];
    __syncthreads();
    int chunk = (E + PB - 1) / PB;
    int beg = j * chunk, end = min(beg + chunk, E);
    for (int e = beg + t; e < end; e += SBLK) {
        unsigned d = (unsigned)NTL(&dst[e]);
        unsigned s = (unsigned)NTL(&src[e]);
        int slot = atomicAdd(&cur[d >> BSH], 1);          // LDS cursor
        epart[slot] = ((d & 1023u) << 19) | s;            // 29 bits
    }
}

// per-bucket degree + node init (deg = in-count + 1 self-loop)
__global__ __launch_bounds__(SBLK)
void bucket_init(const unsigned* __restrict__ epart, const int* __restrict__ base,
                 const int* __restrict__ rl, const int* __restrict__ flag,
                 float* __restrict__ dinv, unsigned* __restrict__ v0, int N) {
    __shared__ int cnt[1024];
    int b = blockIdx.x, t = threadIdx.x;
    cnt[t] = 0;
    __syncthreads();
    int beg = base[b], end = base[b + 1];
    for (int e = beg + t; e < end; e += SBLK)
        atomicAdd(&cnt[NTL(&epart[e]) >> 19], 1);
    __syncthreads();
    int node = b * 1024 + t;
    if (node < N) {
        int v = (*flag) ? rl[node] : rl[2 * node];
        float d = (float)cnt[t] + 1.0f;
        dinv[node] = 1.0f / d;
        float rs = rsqrtf(d);
        v0[node] = packbf2(rs * ((float)v * (1.0f / 20000.0f)), rs);
    }
}

__global__ void coeffs(const float* __restrict__ W1, const float* __restrict__ b1,
                       const float* __restrict__ W2, const float* __restrict__ b2,
                       const float* __restrict__ W3, const float* __restrict__ b3,
                       const float* __restrict__ W4, const float* __restrict__ b4,
                       float* __restrict__ c) {
    __shared__ float p3[16], q3[16], r3[16];
    int t = threadIdx.x;
    if (t == 0) {
        float p2[8], q2[8];
        for (int j = 0; j < 8; ++j) {
            float s1 = 0.f, s2 = 0.f;
            for (int k = 0; k < 4; ++k) {
                float w = W2[k * 8 + j];
                s1 += W1[k] * w;
                s2 += b1[k] * w;
            }
            p2[j] = s1; q2[j] = s2;
        }
        for (int m = 0; m < 16; ++m) {
            float s1 = 0.f, s2 = 0.f, s3 = 0.f;
            for (int j = 0; j < 8; ++j) {
                float w = W3[j * 16 + m];
                s1 += p2[j] * w; s2 += q2[j] * w;
                s3 += b2[j] * w;
            }
            p3[m] = s1; q3[m] = s2; r3[m] = s3;
        }
    }
    __syncthreads();
    if (t < 32) {
        float c4 = 0.f, c3 = 0.f, c2 = 0.f, c1 = 0.f;
        for (int k = 0; k < 16; ++k) {
            float w = W4[k * 32 + t];
            c4 += p3[k] * w; c3 += q3[k] * w; c2 += r3[k] * w;
            c1 += b3[k] * w;
        }
        c[t] = c4; c[32 + t] = c3; c[64 + t] = c2; c[96 + t] = c1;
    }
}

// one sweep: block per bucket (1024 nodes), nt bf16x2 gathers (L1 bypass),
// 8-deep in-flight loads, fp32 LDS accumulation, coalesced stores.
__global__ __launch_bounds__(SBLK)
void gather_pass(const unsigned* __restrict__ ep, const int* __restrict__ base,
                 const unsigned* __restrict__ vin, unsigned* __restrict__ vout,
                 const float* __restrict__ dinv, float* __restrict__ zsave, int N) {
    __shared__ float accA[1024], accB[1024];
    int b = blockIdx.x, t = threadIdx.x;
    accA[t] = 0.f; accB[t] = 0.f;
    __syncthreads();
    int beg = base[b], end = base[b + 1];
    int e = beg + t;
    for (; e + 7 * SBLK < end; e += 8 * SBLK) {
        unsigned p0 = NTL(&ep[e]);
        unsigned p1 = NTL(&ep[e + SBLK]);
        unsigned p2 = NTL(&ep[e + 2 * SBLK]);
        unsigned p3 = NTL(&ep[e + 3 * SBLK]);
        unsigned p4 = NTL(&ep[e + 4 * SBLK]);
        unsigned p5 = NTL(&ep[e + 5 * SBLK]);
        unsigned p6 = NTL(&ep[e + 6 * SBLK]);
        unsigned p7 = NTL(&ep[e + 7 * SBLK]);
        unsigned u0 = NTL(&vin[p0 & 0x7FFFFu]);
        unsigned u1 = NTL(&vin[p1 & 0x7FFFFu]);
        unsigned u2 = NTL(&vin[p2 & 0x7FFFFu]);
        unsigned u3 = NTL(&vin[p3 & 0x7FFFFu]);
        unsigned u4 = NTL(&vin[p4 & 0x7FFFFu]);
        unsigned u5 = NTL(&vin[p5 & 0x7FFFFu]);
        unsigned u6 = NTL(&vin[p6 & 0x7FFFFu]);
        unsigned u7 = NTL(&vin[p7 & 0x7FFFFu]);
        atomicAdd(&accA[p0 >> 19], bf2f(u0 & 0xFFFFu)); atomicAdd(&accB[p0 >> 19], bf2f(u0 >> 16));
        atomicAdd(&accA[p1 >> 19], bf2f(u1 & 0xFFFFu)); atomicAdd(&accB[p1 >> 19], bf2f(u1 >> 16));
        atomicAdd(&accA[p2 >> 19], bf2f(u2 & 0xFFFFu)); atomicAdd(&accB[p2 >> 19], bf2f(u2 >> 16));
        atomicAdd(&accA[p3 >> 19], bf2f(u3 & 0xFFFFu)); atomicAdd(&accB[p3 >> 19], bf2f(u3 >> 16));
        atomicAdd(&accA[p4 >> 19], bf2f(u4 & 0xFFFFu)); atomicAdd(&accB[p4 >> 19], bf2f(u4 >> 16));
        atomicAdd(&accA[p5 >> 19], bf2f(u5 & 0xFFFFu)); atomicAdd(&accB[p5 >> 19], bf2f(u5 >> 16));
        atomicAdd(&accA[p6 >> 19], bf2f(u6 & 0xFFFFu)); atomicAdd(&accB[p6 >> 19], bf2f(u6 >> 16));
        atomicAdd(&accA[p7 >> 19], bf2f(u7 & 0xFFFFu)); atomicAdd(&accB[p7 >> 19], bf2f(u7 >> 16));
    }
    for (; e < end; e += SBLK) {
        unsigned p = NTL(&ep[e]);
        unsigned u = NTL(&vin[p & 0x7FFFFu]);
        atomicAdd(&accA[p >> 19], bf2f(u & 0xFFFFu)); atomicAdd(&accB[p >> 19], bf2f(u >> 16));
    }
    __syncthreads();
    int node = b * 1024 + t;
    if (node < N) {
        unsigned self = vin[node];
        float di = dinv[node];
        float ox = (accA[t] + bf2f(self & 0xFFFFu)) * di;
        float oy = (accB[t] + bf2f(self >> 16)) * di;
        vout[node] = packbf2(ox, oy);
        if (zsave) zsave[node] = oy;     // fp32, pre-rounding
    }
}

__global__ void write_out(const unsigned* __restrict__ vfin, const float* __restrict__ z1,
                          const float* __restrict__ z2, const float* __restrict__ z3,
                          const float* __restrict__ dinv, const float* __restrict__ c,
                          const float* __restrict__ b4,
                          float* __restrict__ out, int N) {
    int t = blockIdx.x * blockDim.x + threadIdx.x;
    int i = t >> 5, f = t & 31;
    if (i < N) {
        float sq = rsqrtf(dinv[i]);  // = sqrt(deg)
        float vx = bf2f(vfin[i] & 0xFFFFu);
        float v = sq * (vx * c[f] + z3[i] * c[32 + f] + z2[i] * c[64 + f]
                        + z1[i] * c[96 + f])
                  + b4[f];
        out[(size_t)i * 32 + f] = v;
    }
}

extern "C" void kernel_launch(void* const* d_in, const int* in_sizes, int n_in,
                              void* d_out, int out_size, void* d_ws, size_t ws_size,
                              hipStream_t stream) {
    const int N = in_sizes[0];
    const int E = in_sizes[1] / 2;
    const int* rl  = (const int*)d_in[0];
    const int* src = (const int*)d_in[1];
    const int* dst = src + E;
    const float* W1 = (const float*)d_in[2];
    const float* b1 = (const float*)d_in[3];
    const float* W2 = (const float*)d_in[4];
    const float* b2 = (const float*)d_in[5];
    const float* W3 = (const float*)d_in[6];
    const float* b3 = (const float*)d_in[7];
    const float* W4 = (const float*)d_in[8];
    const float* b4 = (const float*)d_in[9];

    // workspace (~15 MB)
    float*    dinv = (float*)d_ws;               // N
    unsigned* v0   = (unsigned*)(dinv + N);      // N (packed bf16x2)
    unsigned* v1   = v0 + N;                     // N
    float*    z1   = (float*)(v1 + N);           // N
    float*    z2   = z1 + N;                     // N
    float*    z3   = z2 + N;                     // N
    int*      table = (int*)(z3 + N);            // PB*NB ints (512 KB)
    int*      btot  = table + PB * NB;           // NB
    int*      bbase = btot + NB;                 // NB+1
    float*    c     = (float*)(bbase + NB + 1);  // 128
    int*      flag  = (int*)(c + 128);           // 1

    // packed partitioned edges live in d_out (scratch until write_out)
    unsigned* epart = (unsigned*)d_out;          // E uint32 (32 MB of 64 MB)

    const int gbB = (N + 1023) / 1024;           // buckets containing nodes (489)

    hipMemsetAsync(flag, 0, sizeof(int), stream);
    probe_i64<<<1, BLK, 0, stream>>>(rl, flag);

    // radix partition by dst bucket — zero global atomics
    bucket_count<<<PB, SBLK, 0, stream>>>(dst, table, E);
    bucket_tot<<<(NB + BLK - 1) / BLK, BLK, 0, stream>>>(table, btot);
    scan_base<<<1, BLK, 0, stream>>>(btot, bbase);
    scan_table<<<(NB + BLK - 1) / BLK, BLK, 0, stream>>>(table, bbase);
    scatter<<<PB, SBLK, 0, stream>>>(src, dst, table, epart, E);

    bucket_init<<<gbB, SBLK, 0, stream>>>(epart, bbase, rl, flag, dinv, v0, N);
    coeffs<<<1, 64, 0, stream>>>(W1, b1, W2, b2, W3, b3, W4, b4, c);

    // 4 propagation sweeps, ping-pong v0<->v1
    gather_pass<<<gbB, SBLK, 0, stream>>>(epart, bbase, v0, v1, dinv, z1, N);
    gather_pass<<<gbB, SBLK, 0, stream>>>(epart, bbase, v1, v0, dinv, z2, N);
    gather_pass<<<gbB, SBLK, 0, stream>>>(epart, bbase, v0, v1, dinv, z3, N);
    gather_pass<<<gbB, SBLK, 0, stream>>>(epart, bbase, v1, v0, dinv, (float*)nullptr, N);

    write_out<<<(N * 32 + BLK - 1) / BLK, BLK, 0, stream>>>(
        v0, z1, z2, z3, dinv, c, b4, (float*)d_out, N);
}